// Round 7
// baseline (4448.159 us; speedup 1.0000x reference)
//
#include <hip/hip_runtime.h>
#include <stdint.h>
#include <stddef.h>

// Problem constants
constexpr int V = 32000, E = 256, H = 512, B = 64, T = 512;
constexpr int NTHR = 512;        // 8 waves; wave w owns gate-row tile [16w,16w+16)
constexpr int NBLK = 64;         // 4 groups x 16 blocks
constexpr int BATG = 16;         // batches per group (M = 16)
constexpr int HPB = 32;          // hidden units per block (128 gate rows)

// LDS: gate-tile exchange, double-buffered [2][128 rows * 17]
constexpr int GST = 17;
constexpr int GSZ = 128 * GST;                     // floats per buffer
constexpr int LDS_BYTES = 2 * GSZ * 4;             // 17408 B

// ws layout (dwords): [0,512): per-wave flags, 4 groups x 128;
//                     [1024, 1024+2*BHW): packed bf16-pair h ping-pong
constexpr int FPG = 128;
constexpr int HW_BASE = 1024;
constexpr int BHW = B * 256;     // dwords per h buffer (B batches x 512 bf16 /2)

// Output layout (flat fp32): output | hT | cT | mask
constexpr size_t OUT_HT   = (size_t)B * T * H;
constexpr size_t OUT_CT   = OUT_HT + (size_t)B * H;
constexpr size_t OUT_MASK = OUT_CT + (size_t)B * H;

typedef __attribute__((ext_vector_type(8))) short short8;   // 8 bf16
typedef __attribute__((ext_vector_type(4))) float f32x4;
typedef __attribute__((ext_vector_type(4))) unsigned int u32x4;

__device__ __forceinline__ unsigned short f2bf(float f) {   // RNE fp32->bf16
  uint32_t u = __builtin_bit_cast(uint32_t, f);
  return (unsigned short)((u + 0x7fffu + ((u >> 16) & 1u)) >> 16);
}
__device__ __forceinline__ short8 pack_bf8(float4 v0, float4 v1) {
  short8 r;
  r[0] = (short)f2bf(v0.x); r[1] = (short)f2bf(v0.y);
  r[2] = (short)f2bf(v0.z); r[3] = (short)f2bf(v0.w);
  r[4] = (short)f2bf(v1.x); r[5] = (short)f2bf(v1.y);
  r[6] = (short)f2bf(v1.z); r[7] = (short)f2bf(v1.w);
  return r;
}
__device__ __forceinline__ float sigmoidf_fast(float x) {
  return 1.f / (1.f + __expf(-x));
}
__device__ __forceinline__ float tanhf_fast(float x) {   // 1 - 2/(e^2x+1)
  return 1.f - 2.f / (__expf(2.f * x) + 1.f);            // inf-safe both tails
}
// MALL-coherent relaxed agent ops (bypass per-XCD L2; no cache maintenance)
__device__ __forceinline__ void st_word(uint32_t* p, uint32_t v) {
  __hip_atomic_store(p, v, __ATOMIC_RELAXED, __HIP_MEMORY_SCOPE_AGENT);
}
__device__ __forceinline__ int ld_flag(const int* p) {
  return __hip_atomic_load(p, __ATOMIC_RELAXED, __HIP_MEMORY_SCOPE_AGENT);
}
__device__ __forceinline__ void st_flag(int* p, int v) {
  __hip_atomic_store(p, v, __ATOMIC_RELAXED, __HIP_MEMORY_SCOPE_AGENT);
}

// h fetch: wave's full K=512 slice for its batch — 16x dwordx4, one wait.
#define LDH(i, off) "global_load_dwordx4 %" #i ", %16, off offset:" #off " sc1\n\t"
__device__ __forceinline__ void ld_h_16x4(const uint32_t* p,
    u32x4& r0, u32x4& r1, u32x4& r2, u32x4& r3,
    u32x4& r4, u32x4& r5, u32x4& r6, u32x4& r7,
    u32x4& r8, u32x4& r9, u32x4& r10, u32x4& r11,
    u32x4& r12, u32x4& r13, u32x4& r14, u32x4& r15) {
  asm volatile(
      LDH(0, 0) LDH(1, 64) LDH(2, 128) LDH(3, 192)
      LDH(4, 256) LDH(5, 320) LDH(6, 384) LDH(7, 448)
      LDH(8, 512) LDH(9, 576) LDH(10, 640) LDH(11, 704)
      LDH(12, 768) LDH(13, 832) LDH(14, 896) LDH(15, 960)
      "s_waitcnt vmcnt(0)"
      : "=&v"(r0), "=&v"(r1), "=&v"(r2), "=&v"(r3),
        "=&v"(r4), "=&v"(r5), "=&v"(r6), "=&v"(r7),
        "=&v"(r8), "=&v"(r9), "=&v"(r10), "=&v"(r11),
        "=&v"(r12), "=&v"(r13), "=&v"(r14), "=&v"(r15)
      : "v"(p)
      : "memory");
}

__global__ void __launch_bounds__(NTHR, 1)
lstm_mfma(const int* __restrict__ inputs, const int* __restrict__ lengths,
          const int* __restrict__ resets, const float* __restrict__ emb,
          const float* __restrict__ W_ih, const float* __restrict__ W_hh,
          const float* __restrict__ b_ih, const float* __restrict__ b_hh,
          float* __restrict__ out, int* __restrict__ ws_flags,
          uint32_t* __restrict__ hw) {
  extern __shared__ char lds[];
  float* Gl = (float*)lds;        // [t&1][n(128)*17 + m(16)]

  const int tid = threadIdx.x;
  const int blk = blockIdx.x;
  const int grp = blk & 3;        // batch group 0..3
  const int rq = blk >> 2;        // block rank in group 0..15
  const int khid = rq * HPB;      // hidden base (32 dims)
  const int b0 = grp * BATG;
  int* flags = ws_flags + grp * FPG;

  const int w = tid >> 6;         // wave 0..7 -> n-tile rows [16w, 16w+16)
  const int L = tid & 63;
  const int lc = L & 15;          // A: batch m | B: row-in-tile
  const int q = L >> 4;           // quad

  // ---- persistent W fragments (bf16), full K per wave: wf[s], k = 32s + 8q
  const int n = 16 * w + lc;                        // gate row in block
  const int grow = (n >> 5) * H + khid + (n & 31);  // global gate row
  short8 wf[24];
  #pragma unroll
  for (int s = 0; s < 24; ++s) {
    const int k = 32 * s + 8 * q;
    const float* src = (k < 512) ? (W_hh + (size_t)grow * H + k)
                                 : (W_ih + (size_t)grow * E + (k - 512));
    wf[s] = pack_bf8(*(const float4*)src, *(const float4*)(src + 4));
  }
  const float bias_n = b_ih[grow] + b_hh[grow];     // folded into MFMA C-init

  const int jj = tid & 31;        // epilogue: hidden dim 0..31
  const int bb = tid >> 5;        // epilogue: batch 0..15
  const int len_bb = lengths[b0 + bb];

  {  // mask output, fused: 64 blocks x 512 threads = B*T
    int i = blk * 512 + tid;
    int mb = i >> 9, mt = i & (T - 1);
    out[OUT_MASK + i] = (mt < lengths[mb]) ? 1.f : 0.f;
  }
  // No init barrier: flags gate on ws poison (0xAAAAAAAA < 1 signed);
  // h buffer is not read at t=0; Gl first read after the t=0 sync.

  float carry_h = 0.f, carry_c = 0.f;

  for (int t = 0; t < T; ++t) {
    // ---- pre-poll independent work
    const float rr = (float)resets[(b0 + bb) * T + t];
    const int tok = inputs[(b0 + lc) * T + t];
    f32x4 acc = {bias_n, bias_n, bias_n, bias_n};   // bias as C-init

    #pragma unroll
    for (int s = 16; s < 24; ++s) {                 // emb side: k-512 = 32(s-16)+8q
      const float* eb = emb + (size_t)tok * E + 32 * (s - 16) + 8 * q;
      short8 a = pack_bf8(*(const float4*)eb, *(const float4*)(eb + 4));
      acc = __builtin_amdgcn_mfma_f32_16x16x32_bf16(a, wf[s], acc, 0, 0, 0);
    }

    if (t > 0) {
      // ---- poll the group's 128 per-wave flags (every wave, no release hop)
      for (;;) {
        int v0 = ld_flag(flags + L);
        int v1 = ld_flag(flags + 64 + L);
        if (__all(v0 >= t && v1 >= t)) break;
        __builtin_amdgcn_s_sleep(1);
      }
      // ---- h side: full K=512 for batch lc, one batched issue, one wait
      const uint32_t* p = hw + (size_t)(t & 1) * BHW + (size_t)(b0 + lc) * 256 + 4 * q;
      u32x4 r0, r1, r2, r3, r4, r5, r6, r7, r8, r9, r10, r11, r12, r13, r14, r15;
      ld_h_16x4(p, r0, r1, r2, r3, r4, r5, r6, r7,
                r8, r9, r10, r11, r12, r13, r14, r15);
      u32x4 rl[16] = {r0, r1, r2, r3, r4, r5, r6, r7,
                      r8, r9, r10, r11, r12, r13, r14, r15};
      #pragma unroll
      for (int s = 0; s < 16; ++s) {
        short8 a = __builtin_bit_cast(short8, rl[s]);  // bf16 pairs, in order
        acc = __builtin_amdgcn_mfma_f32_16x16x32_bf16(a, wf[s], acc, 0, 0, 0);
      }
    }

    // ---- exchange tile through LDS: D[m=4q+reg][n] -> Gl[n*17 + m]
    float* Gc = Gl + (t & 1) * GSZ;
    *(f32x4*)(Gc + n * GST + 4 * q) = acc;
    __syncthreads();              // the ONLY per-step block sync

    // ---- epilogue: 4 LDS reads + LSTM math (all 512 threads)
    const float ig = sigmoidf_fast(Gc[jj * GST + bb]);
    const float fg = sigmoidf_fast(Gc[(32 + jj) * GST + bb]);
    const float gg = tanhf_fast(Gc[(64 + jj) * GST + bb]);
    const float og = sigmoidf_fast(Gc[(96 + jj) * GST + bb]);
    const float c_new = fg * carry_c + ig * gg;
    const float h_new = og * tanhf_fast(c_new);
    const bool live = (t < len_bb);
    const float h_next = live ? h_new : carry_h;    // carries are exact fp32
    const float c_next = live ? c_new : carry_c;
    carry_h = h_next * (1.f - rr);
    carry_c = c_next * (1.f - rr);

    if (t < T - 1) {
      // pack 2 adjacent hidden dims per dword; even lanes store (32/wave)
      const float ph = __shfl(carry_h, L ^ 1);
      if ((tid & 1) == 0) {
        const uint32_t word = (uint32_t)f2bf(carry_h) | ((uint32_t)f2bf(ph) << 16);
        st_word(hw + (size_t)((t + 1) & 1) * BHW +
                    (size_t)(b0 + bb) * 256 + 16 * rq + (jj >> 1), word);
      }
      // per-wave drain, then per-wave flag post — no block-wide sync
      asm volatile("s_waitcnt vmcnt(0)" ::: "memory");
      if (L == 0) st_flag(&flags[rq * 8 + w], t + 1);
    }
    // HBM output store off the critical path
    out[((size_t)(b0 + bb) * T + t) * H + khid + jj] = h_next;
  }
  out[OUT_HT + (size_t)(b0 + bb) * H + khid + jj] = carry_h;
  out[OUT_CT + (size_t)(b0 + bb) * H + khid + jj] = carry_c;
}

extern "C" void kernel_launch(void* const* d_in, const int* in_sizes, int n_in,
                              void* d_out, int out_size, void* d_ws, size_t ws_size,
                              hipStream_t stream) {
  const int* inputs    = (const int*)d_in[0];
  const int* lengths   = (const int*)d_in[1];
  const int* resets    = (const int*)d_in[2];
  const float* emb     = (const float*)d_in[3];
  const float* W_ih    = (const float*)d_in[4];
  const float* W_hh    = (const float*)d_in[5];
  const float* b_ih    = (const float*)d_in[6];
  const float* b_hh    = (const float*)d_in[7];
  float* out = (float*)d_out;

  // ws: flags at [0,2KB) (poison 0xAA = negative, gates until first post);
  //     packed h ping-pong at [4KB, 4KB+256KB).
  int* ws_flags = (int*)d_ws;
  uint32_t* hw = (uint32_t*)d_ws + HW_BASE;

  lstm_mfma<<<NBLK, NTHR, LDS_BYTES, stream>>>(
      inputs, lengths, resets, emb, W_ih, W_hh, b_ih, b_hh, out, ws_flags, hw);
}